// Round 5
// baseline (229.735 us; speedup 1.0000x reference)
//
#include <hip/hip_runtime.h>

#define BATCH 4
#define CH    256
#define NPIX  4096
#define CQD   32

typedef __bf16 bf16;
typedef bf16 bf16x8 __attribute__((ext_vector_type(8)));
typedef bf16 bf16x4 __attribute__((ext_vector_type(4)));
typedef float f32x4 __attribute__((ext_vector_type(4)));
typedef float f32x16 __attribute__((ext_vector_type(16)));

#define MFMA16 __builtin_amdgcn_mfma_f32_16x16x32_bf16
#define MFMA32 __builtin_amdgcn_mfma_f32_32x32x16_bf16

#define GLOAD_LDS16(g, l) __builtin_amdgcn_global_load_lds( \
    (const __attribute__((address_space(1))) void*)(g),     \
    (__attribute__((address_space(3))) void*)(l), 16, 0, 0)

// Single-instruction 2^x (v_exp_f32). Precise exp2f() lowers to a ~6-op
// ocml sequence (R14 post-mortem: VALUBusy 29.6->41%, attn +2.1us).
__device__ __forceinline__ float fast_exp2(float x) {
#if __has_builtin(__builtin_amdgcn_exp2f)
    return __builtin_amdgcn_exp2f(x);
#else
    float r;
    asm("v_exp_f32 %0, %1" : "=v"(r) : "v"(x));
    return r;
#endif
}

// ---------------------------------------------------------------------------
// Kernel 0: pack weights to bf16, stacked [320][256] (q-scale folded).
// q rows fold BOTH the 1/sqrt(N)=1/64 scale AND log2(e) so the attn softmax
// is a single v_exp_f32 per element.
// ---------------------------------------------------------------------------
__global__ __launch_bounds__(256) void prep_kernel(
    const float* __restrict__ Wq, const float* __restrict__ bq,
    const float* __restrict__ Wk, const float* __restrict__ bk,
    const float* __restrict__ Wv, const float* __restrict__ bv,
    bf16* __restrict__ Wb, float* __restrict__ bb)
{
    int r = blockIdx.x, c = threadIdx.x;
    const float* W; const float* bs; float sc; int rr;
    if (r < 32)      { W = Wq; bs = bq; sc = 0.015625f * 1.44269504088896340736f; rr = r; }
    else if (r < 64) { W = Wk; bs = bk; sc = 1.0f;      rr = r - 32; }
    else             { W = Wv; bs = bv; sc = 1.0f;      rr = r - 64; }
    Wb[(size_t)r * CH + c] = (bf16)(W[(size_t)rr * CH + c] * sc);
    if (c == 0) bb[r] = bs[rr] * sc;
}

// ---------------------------------------------------------------------------
// Kernel 1: fused 1x1-conv projections via MFMA (unchanged from R6).
// ---------------------------------------------------------------------------
__global__ __launch_bounds__(256) void proj_kernel(
    const float* __restrict__ x,
    const bf16* __restrict__ Wb, const float* __restrict__ bb,
    bf16* __restrict__ qp, bf16* __restrict__ kp, bf16* __restrict__ vT)
{
    __shared__ __align__(16) bf16 xT[32][264];
    __shared__ __align__(16) bf16 vstage[4][16][40];

    const int t  = threadIdx.x;
    const int b  = blockIdx.x >> 7;
    const int n0 = (blockIdx.x & 127) << 5;
    const int w    = t >> 6;
    const int lane = t & 63;
    const int l16  = t & 15;
    const int quad = (t & 63) >> 4;

    const float* xb = x + (size_t)b * CH * NPIX;
#pragma unroll
    for (int j = 0; j < 8; ++j) {
        int id = t + j * 256;
        int c  = id >> 3;
        int n4 = (id & 7) << 2;
        float4 vv = *(const float4*)(xb + (size_t)c * NPIX + n0 + n4);
        xT[n4 + 0][c] = (bf16)vv.x;
        xT[n4 + 1][c] = (bf16)vv.y;
        xT[n4 + 2][c] = (bf16)vv.z;
        xT[n4 + 3][c] = (bf16)vv.w;
    }
    __syncthreads();

    for (int rt = 0; rt < 5; ++rt) {
        int ro = w * 80 + rt * 16;
        int kind = (ro < 32) ? 0 : (ro < 64) ? 1 : 2;

        bf16x8 afrag[8];
        const bf16* wrow = Wb + (size_t)(ro + l16) * CH + quad * 8;
#pragma unroll
        for (int kc = 0; kc < 8; ++kc)
            afrag[kc] = *(const bf16x8*)(wrow + kc * 32);
        float bv4[4];
#pragma unroll
        for (int r = 0; r < 4; ++r) bv4[r] = bb[ro + quad * 4 + r];

#pragma unroll
        for (int nt = 0; nt < 2; ++nt) {
            f32x4 acc = {0.f, 0.f, 0.f, 0.f};
#pragma unroll
            for (int kc = 0; kc < 8; ++kc) {
                bf16x8 bfr = *(const bf16x8*)&xT[nt * 16 + l16][kc * 32 + quad * 8];
                acc = MFMA16(afrag[kc], bfr, acc, 0, 0, 0);
            }
            if (kind != 2) {
                bf16x4 pk;
#pragma unroll
                for (int r = 0; r < 4; ++r)
                    pk[r] = (bf16)(acc[r] + bv4[r]);
                int n = n0 + nt * 16 + l16;
                int col = (kind == 0 ? ro : ro - 32) + quad * 4;
                bf16* dst = (kind == 0) ? qp : kp;
                *(bf16x4*)&dst[((size_t)b * NPIX + n) * CQD + col] = pk;
            } else {
#pragma unroll
                for (int r = 0; r < 4; ++r)
                    vstage[w][quad * 4 + r][nt * 16 + l16] = (bf16)(acc[r] + bv4[r]);
            }
        }
        if (kind == 2) {
            int vrow = lane >> 2, vcc = lane & 3;
            bf16x8 chunk = *(const bf16x8*)&vstage[w][vrow][vcc * 8];
            *(bf16x8*)&vT[((size_t)b * CH + (ro - 64) + vrow) * NPIX + n0 + vcc * 8] = chunk;
        }
    }
}

// ---------------------------------------------------------------------------
// Kernel 2: split-K flash attention, R15. Main loop = EXACT R10 structure
// (prefetch at iter-top; QK reg-MFMA + softmax VALU hide the L2 latency;
// 2 barriers/iter; kf reg-dbuf; 80 KB LDS; launch_bounds(256,2)).
// Deltas vs R10:
//  (a) softmax exp = single v_exp_f32 (log2e pre-folded into Wq/bq by prep).
//  (b) FUSED split-K fixup: each block writes Opart/Lpart, then
//      syncthreads + threadfence + atomicAdd(cnt[b*32+qt]); the last of the
//      S sibling blocks combines its 128 rows (removes combine_kernel launch
//      + its drain; combine starts per-row-group as soon as siblings finish).
//      Flag parked in dead PbS space: +0 LDS (80 KB cap = 2 blocks/CU).
// R11-R13 ledger: 512-thr (reg spill), ch-split (dup softmax), prefetch-
// after-barrier1 (LDS port contention) all lost — schedule stays R10.
// ---------------------------------------------------------------------------
template<int S, bool DIRECT>
__global__ __launch_bounds__(256, 2) void attn_kernel(
    const bf16* __restrict__ qp, const bf16* __restrict__ kp,
    const bf16* __restrict__ vT,
    bf16* __restrict__ Opart, float* __restrict__ Lpart,
    int* __restrict__ cnt,
    float* __restrict__ out)
{
    __shared__ __align__(16) bf16 Vt[2][256][64];   // 64 KB
    __shared__ __align__(16) bf16 PbS[128][64];     // 16 KB, block-shared

    const int t    = threadIdx.x;
    const int bid  = blockIdx.x;
    const int s    = bid % S;
    const int tq   = bid / S;
    const int b    = tq >> 5;
    const int qt   = tq & 31;
    const int n0   = qt << 7;
    const int w    = t >> 6;
    const int lane = t & 63;
    const int l16  = t & 15;
    const int quad = (t & 63) >> 4;
    const int sw   = l16 & 7;
    const int l32  = lane & 31;
    const int h    = lane >> 5;
    const int qh   = w >> 1;            // PV q-half (64 rows)
    const int chb  = (w & 1) * 128;     // PV channel half

    const bf16* qpb = qp + ((size_t)b * NPIX + n0 + w * 32) * CQD;
    bf16x8 qfrag[2];
    qfrag[0] = *(const bf16x8*)(qpb + (size_t)l16 * CQD + quad * 8);
    qfrag[1] = *(const bf16x8*)(qpb + (size_t)(16 + l16) * CQD + quad * 8);

    f32x16 o[2][4];   // [t32 q-tile][ct ch-tile], D[m=q][n=ch]
#pragma unroll
    for (int i = 0; i < 2; ++i)
#pragma unroll
        for (int j = 0; j < 4; ++j)
#pragma unroll
            for (int r = 0; r < 16; ++r) o[i][j][r] = 0.f;
    float lsum[2] = {0.f, 0.f};

    const bf16* kpb = kp + (size_t)b * NPIX * CQD;
    const bf16* vTb = vT + (size_t)b * CH * NPIX;
    const int k0 = s * (NPIX / S);
    const int iters = NPIX / S / 64;

    const int vrow_off = lane >> 3;
    const int vchunk   = (lane & 7) ^ vrow_off;
    auto issue_vt = [&](int buf, int m0) {
#pragma unroll
        for (int j = 0; j < 8; ++j) {
            int rowbase = j * 32 + w * 8;
            const bf16* src = vTb + (size_t)(rowbase + vrow_off) * NPIX + m0 + vchunk * 8;
            GLOAD_LDS16(src, &Vt[buf][rowbase][0]);
        }
    };
    auto load_kf = [&](int m0, bf16x8* kf) {
#pragma unroll
        for (int mt = 0; mt < 4; ++mt)
            kf[mt] = *(const bf16x8*)(kpb + (size_t)(m0 + mt * 16 + l16) * CQD + quad * 8);
    };

    bf16x8 kfa[4], kfb[4];
    issue_vt(0, k0);
    load_kf(k0, kfa);
    __syncthreads();

    for (int mi = 0; mi < iters; ++mi) {
        const int cur = mi & 1;
        const int m0  = k0 + (mi << 6);
        if (mi + 1 < iters) {
            issue_vt(cur ^ 1, m0 + 64);
            load_kf(m0 + 64, kfb);
        }

        // S^T tiles for this wave's 32 q: D[key=mt*16+quad*4+r][q=w*32+g*16+l16]
        f32x4 sv[2][4];
#pragma unroll
        for (int mt = 0; mt < 4; ++mt) {
            f32x4 z = {0.f, 0.f, 0.f, 0.f};
            sv[0][mt] = MFMA16(kfa[mt], qfrag[0], z, 0, 0, 0);
            sv[1][mt] = MFMA16(kfa[mt], qfrag[1], z, 0, 0, 0);
        }

        // p = 2^s (log2e pre-folded, m=0) -> shared PbS[q][key], swizzled
#pragma unroll
        for (int g = 0; g < 2; ++g) {
            float rs = 0.f;
#pragma unroll
            for (int mt = 0; mt < 4; ++mt) {
                bf16x4 pk;
#pragma unroll
                for (int r = 0; r < 4; ++r) {
                    float e = fast_exp2(sv[g][mt][r]);
                    rs += e;
                    pk[r] = (bf16)e;
                }
                int slot = (2 * mt + (quad >> 1)) ^ sw;
                *(bf16x4*)&PbS[w * 32 + g * 16 + l16][slot * 8 + (quad & 1) * 4] = pk;
            }
            lsum[g] += rs;
        }
        __syncthreads();   // PbS visible to all waves (also drains prefetch)

        // PV: A = P[32q x 16k] frags from PbS, B = V[16k x 32ch] from Vt.
        bf16x8 pA[2][4];
#pragma unroll
        for (int t32 = 0; t32 < 2; ++t32)
#pragma unroll
            for (int kg = 0; kg < 4; ++kg) {
                int row = qh * 64 + t32 * 32 + l32;
                pA[t32][kg] = *(const bf16x8*)&PbS[row][((2 * kg + h) ^ (l32 & 7)) * 8];
            }
#pragma unroll
        for (int ct = 0; ct < 4; ++ct) {
            int vrow = chb + ct * 32 + l32;
            bf16x8 vB[4];
#pragma unroll
            for (int kg = 0; kg < 4; ++kg)
                vB[kg] = *(const bf16x8*)&Vt[cur][vrow][((2 * kg + h) ^ (l32 & 7)) * 8];
#pragma unroll
            for (int t32 = 0; t32 < 2; ++t32)
#pragma unroll
                for (int kg = 0; kg < 4; ++kg)
                    o[t32][ct] = MFMA32(pA[t32][kg], vB[kg], o[t32][ct], 0, 0, 0);
        }
        __syncthreads();   // PbS/Vt consumed before next iter's writes/staging
#pragma unroll
        for (int i = 0; i < 4; ++i) kfa[i] = kfb[i];
    }

    // final l: reduce quad partials; rows w*32+g*16+l16
    float l_g[2];
#pragma unroll
    for (int g = 0; g < 2; ++g) {
        float v = lsum[g];
        v += __shfl_xor(v, 16);
        v += __shfl_xor(v, 32);
        l_g[g] = v;
    }
    float* lsh = (float*)PbS;          // PbS dead after final barrier
    if (quad == 0) {
#pragma unroll
        for (int g = 0; g < 2; ++g)
            lsh[w * 32 + g * 16 + l16] = l_g[g];
    }
    __syncthreads();

    const size_t prb2 = ((size_t)s * BATCH + b) * NPIX + n0;
    if (!DIRECT && quad == 0) {
#pragma unroll
        for (int g = 0; g < 2; ++g)
            Lpart[prb2 + w * 32 + g * 16 + l16] = l_g[g];
    }

    // epilogue: D layout row(q) = (reg&3)+8*(reg>>2)+4*h, col(ch) = l32.
    bf16* eb = (bf16*)Vt + (size_t)w * 32 * 136;   // wave-private bounce
#pragma unroll
    for (int t32 = 0; t32 < 2; ++t32) {
        float rinv[16];
#pragma unroll
        for (int reg = 0; reg < 16; ++reg) {
            int q_r = (reg & 3) + 8 * (reg >> 2) + 4 * h;
            rinv[reg] = 1.0f / lsh[qh * 64 + t32 * 32 + q_r];
        }
        if (!DIRECT) {
#pragma unroll
            for (int ct = 0; ct < 4; ++ct)
#pragma unroll
                for (int reg = 0; reg < 16; ++reg) {
                    int q_r = (reg & 3) + 8 * (reg >> 2) + 4 * h;
                    eb[q_r * 136 + ct * 32 + l32] = (bf16)(o[t32][ct][reg] * rinv[reg]);
                }
            // 32 rows x 128 ch = 8192 B = 64 lanes x 16B x 8 passes
            int vrow = lane >> 4, vcc = lane & 15;
#pragma unroll
            for (int p = 0; p < 8; ++p) {
                int row = p * 4 + vrow;
                bf16x8 chunk = *(const bf16x8*)&eb[row * 136 + vcc * 8];
                *(bf16x8*)&Opart[(prb2 + qh * 64 + t32 * 32 + row) * CH +
                                 chb + vcc * 8] = chunk;
            }
        } else {
            float* ob = out + (prb2 + qh * 64 + t32 * 32) * CH + chb;
#pragma unroll
            for (int ct = 0; ct < 4; ++ct)
#pragma unroll
                for (int reg = 0; reg < 16; ++reg) {
                    int q_r = (reg & 3) + 8 * (reg >> 2) + 4 * h;
                    ob[(size_t)q_r * CH + ct * 32 + l32] = o[t32][ct][reg] * rinv[reg];
                }
        }
    }

    // ---- fused split-K fixup: last sibling block combines its 128 rows ----
    if (!DIRECT) {
        __syncthreads();                 // all Opart/Lpart stores issued
        __threadfence();                 // release (device scope)
        volatile int* flag = (volatile int*)((int*)PbS + 192);
        if (t == 0)
            *flag = atomicAdd(&cnt[b * 32 + qt], 1);
        __syncthreads();
        if (*flag == S - 1) {
            __threadfence();             // acquire: see siblings' stores
#pragma unroll
            for (int it = 0; it < 8; ++it) {
                int li = it * 256 + t;   // 0..2047
                int r  = li >> 4;        // 0..127
                int cc = (li & 15) * 16; // ch offset
                size_t rb = (size_t)b * NPIX + n0 + r;
                float ls2[S], wsum = 0.f;
#pragma unroll
                for (int sp = 0; sp < S; ++sp) {
                    ls2[sp] = Lpart[(size_t)sp * BATCH * NPIX + rb];
                    wsum += ls2[sp];
                }
                float inv2 = 1.0f / wsum;
                bf16x8 ovv[S][2];
#pragma unroll
                for (int sp = 0; sp < S; ++sp) {
                    const bf16* op = Opart + ((size_t)sp * BATCH * NPIX + rb) * CH + cc;
                    ovv[sp][0] = *(const bf16x8*)op;
                    ovv[sp][1] = *(const bf16x8*)(op + 8);
                }
                float acc2[16];
#pragma unroll
                for (int j = 0; j < 16; ++j) acc2[j] = 0.f;
#pragma unroll
                for (int sp = 0; sp < S; ++sp) {
                    float wn = ls2[sp] * inv2;
#pragma unroll
                    for (int k2 = 0; k2 < 2; ++k2)
#pragma unroll
                        for (int j = 0; j < 8; ++j)
                            acc2[k2 * 8 + j] += wn * (float)ovv[sp][k2][j];
                }
                float* ob2 = out + rb * CH + cc;
#pragma unroll
                for (int k2 = 0; k2 < 4; ++k2) {
                    float4 o4 = {acc2[4 * k2], acc2[4 * k2 + 1],
                                 acc2[4 * k2 + 2], acc2[4 * k2 + 3]};
                    *(float4*)&ob2[4 * k2] = o4;
                }
            }
        }
    }
}

extern "C" void kernel_launch(void* const* d_in, const int* in_sizes, int n_in,
                              void* d_out, int out_size, void* d_ws, size_t ws_size,
                              hipStream_t stream) {
    const float* x  = (const float*)d_in[0];
    const float* Wq = (const float*)d_in[1];
    const float* bq = (const float*)d_in[2];
    const float* Wk = (const float*)d_in[3];
    const float* bk = (const float*)d_in[4];
    const float* Wv = (const float*)d_in[5];
    const float* bv = (const float*)d_in[6];
    float* out = (float*)d_out;

    char* ws = (char*)d_ws;
    const size_t qpB   = (size_t)BATCH * NPIX * CQD * 2;   // 1 MB
    const size_t vTB   = (size_t)BATCH * CH * NPIX * 2;    // 8 MB
    const size_t WbB   = (size_t)320 * CH * 2;             // 160 KB
    const size_t bbB   = 320 * 4 + 768;                    // padded
    const size_t baseB = 2 * qpB + vTB + WbB + bbB;
    const size_t oprtB = (size_t)BATCH * NPIX * CH * 2;    // 8.4 MB per split
    const size_t mlB   = (size_t)BATCH * NPIX * 4;         // 64 KB per split
    const size_t cntB  = 1024;                             // counters, padded

    bf16*  qp = (bf16*)ws;
    bf16*  kp = (bf16*)(ws + qpB);
    bf16*  vT = (bf16*)(ws + 2 * qpB);
    bf16*  Wb = (bf16*)(ws + 2 * qpB + vTB);
    float* bb = (float*)(ws + 2 * qpB + vTB + WbB);

    auto need = [&](int S) { return baseB + (size_t)S * (oprtB + mlB) + cntB; };
    int S = (ws_size >= need(4)) ? 4 : (ws_size >= need(2)) ? 2
          : (ws_size >= need(1)) ? 1 : 0;

    prep_kernel<<<dim3(320), dim3(256), 0, stream>>>(Wq, bq, Wk, bk, Wv, bv, Wb, bb);
    proj_kernel<<<dim3(BATCH * (NPIX / 32)), dim3(256), 0, stream>>>(
        x, Wb, bb, qp, kp, vT);

    if (S > 0) {
        bf16*  Opart = (bf16*)(ws + baseB);
        float* Lpart = (float*)(ws + baseB + (size_t)S * oprtB);
        int*   cnt   = (int*)(ws + baseB + (size_t)S * (oprtB + mlB));
        hipMemsetAsync((void*)cnt, 0, 128 * sizeof(int), stream);
        if (S == 4) {
            attn_kernel<4, false><<<dim3(128 * 4), dim3(256), 0, stream>>>(
                qp, kp, vT, Opart, Lpart, cnt, out);
        } else if (S == 2) {
            attn_kernel<2, false><<<dim3(128 * 2), dim3(256), 0, stream>>>(
                qp, kp, vT, Opart, Lpart, cnt, out);
        } else {
            attn_kernel<1, false><<<dim3(128), dim3(256), 0, stream>>>(
                qp, kp, vT, Opart, Lpart, cnt, out);
        }
    } else {
        attn_kernel<1, true><<<dim3(128), dim3(256), 0, stream>>>(
            qp, kp, vT, nullptr, nullptr, nullptr, out);
    }
}

// Round 6
// 151.169 us; speedup vs baseline: 1.5197x; 1.5197x over previous
//
#include <hip/hip_runtime.h>

#define BATCH 4
#define CH    256
#define NPIX  4096
#define CQD   32

typedef __bf16 bf16;
typedef bf16 bf16x8 __attribute__((ext_vector_type(8)));
typedef bf16 bf16x4 __attribute__((ext_vector_type(4)));
typedef float f32x4 __attribute__((ext_vector_type(4)));
typedef float f32x16 __attribute__((ext_vector_type(16)));

#define MFMA16 __builtin_amdgcn_mfma_f32_16x16x32_bf16
#define MFMA32 __builtin_amdgcn_mfma_f32_32x32x16_bf16

#define GLOAD_LDS16(g, l) __builtin_amdgcn_global_load_lds( \
    (const __attribute__((address_space(1))) void*)(g),     \
    (__attribute__((address_space(3))) void*)(l), 16, 0, 0)

// Single-instruction 2^x (v_exp_f32). Precise exp2f() lowers to a ~6-op
// ocml sequence (R14: VALUBusy 29.6->41%, attn +2.1us). Verified correct in
// R15 (absmax unchanged). R15's slowdown was the threadfence, not this.
__device__ __forceinline__ float fast_exp2(float x) {
#if __has_builtin(__builtin_amdgcn_exp2f)
    return __builtin_amdgcn_exp2f(x);
#else
    return __expf(x * 0.69314718055994530942f);  // fallback: exp(ln2*x)=2^x
#endif
}

// q-scale: 1/sqrt(4096) = 1/64, with log2(e) folded so softmax is bare 2^x.
#define QSCALE (0.015625f * 1.44269504088896340736f)

// ---------------------------------------------------------------------------
// Kernel 1: fused 1x1-conv projections via MFMA. R16: prep_kernel FUSED —
// each block loads the f32 weights directly and converts to bf16 fragments
// in registers (327 KB/block, L2-resident after first touch per XCD; no
// cross-block dataflow, no fences). Removes one dispatch + its boundary.
// ---------------------------------------------------------------------------
__global__ __launch_bounds__(256) void proj_kernel(
    const float* __restrict__ x,
    const float* __restrict__ Wq, const float* __restrict__ bq,
    const float* __restrict__ Wk, const float* __restrict__ bk,
    const float* __restrict__ Wv, const float* __restrict__ bv,
    bf16* __restrict__ qp, bf16* __restrict__ kp, bf16* __restrict__ vT)
{
    __shared__ __align__(16) bf16 xT[32][264];
    __shared__ __align__(16) bf16 vstage[4][16][40];

    const int t  = threadIdx.x;
    const int b  = blockIdx.x >> 7;
    const int n0 = (blockIdx.x & 127) << 5;
    const int w    = t >> 6;
    const int lane = t & 63;
    const int l16  = t & 15;
    const int quad = (t & 63) >> 4;

    const float* xb = x + (size_t)b * CH * NPIX;
#pragma unroll
    for (int j = 0; j < 8; ++j) {
        int id = t + j * 256;
        int c  = id >> 3;
        int n4 = (id & 7) << 2;
        float4 vv = *(const float4*)(xb + (size_t)c * NPIX + n0 + n4);
        xT[n4 + 0][c] = (bf16)vv.x;
        xT[n4 + 1][c] = (bf16)vv.y;
        xT[n4 + 2][c] = (bf16)vv.z;
        xT[n4 + 3][c] = (bf16)vv.w;
    }
    __syncthreads();

    for (int rt = 0; rt < 5; ++rt) {
        int ro = w * 80 + rt * 16;          // 16-row tile; kind uniform in tile
        int kind = (ro < 32) ? 0 : (ro < 64) ? 1 : 2;
        const float* W; const float* bs; float sc; int rr0;
        if (kind == 0)      { W = Wq; bs = bq; sc = QSCALE; rr0 = ro; }
        else if (kind == 1) { W = Wk; bs = bk; sc = 1.0f;   rr0 = ro - 32; }
        else                { W = Wv; bs = bv; sc = 1.0f;   rr0 = ro - 64; }

        // weight fragments: f32 load + scale + cvt (was: bf16 load from Wb)
        bf16x8 afrag[8];
        const float* wrow = W + (size_t)(rr0 + l16) * CH + quad * 8;
#pragma unroll
        for (int kc = 0; kc < 8; ++kc) {
            float4 wa = *(const float4*)(wrow + kc * 32);
            float4 wb2 = *(const float4*)(wrow + kc * 32 + 4);
            bf16x8 af;
            af[0] = (bf16)(wa.x * sc);  af[1] = (bf16)(wa.y * sc);
            af[2] = (bf16)(wa.z * sc);  af[3] = (bf16)(wa.w * sc);
            af[4] = (bf16)(wb2.x * sc); af[5] = (bf16)(wb2.y * sc);
            af[6] = (bf16)(wb2.z * sc); af[7] = (bf16)(wb2.w * sc);
            afrag[kc] = af;
        }
        float bv4[4];
#pragma unroll
        for (int r = 0; r < 4; ++r) bv4[r] = bs[rr0 + quad * 4 + r] * sc;

#pragma unroll
        for (int nt = 0; nt < 2; ++nt) {
            f32x4 acc = {0.f, 0.f, 0.f, 0.f};
#pragma unroll
            for (int kc = 0; kc < 8; ++kc) {
                bf16x8 bfr = *(const bf16x8*)&xT[nt * 16 + l16][kc * 32 + quad * 8];
                acc = MFMA16(afrag[kc], bfr, acc, 0, 0, 0);
            }
            if (kind != 2) {
                bf16x4 pk;
#pragma unroll
                for (int r = 0; r < 4; ++r)
                    pk[r] = (bf16)(acc[r] + bv4[r]);
                int n = n0 + nt * 16 + l16;
                int col = (kind == 0 ? ro : ro - 32) + quad * 4;
                bf16* dst = (kind == 0) ? qp : kp;
                *(bf16x4*)&dst[((size_t)b * NPIX + n) * CQD + col] = pk;
            } else {
#pragma unroll
                for (int r = 0; r < 4; ++r)
                    vstage[w][quad * 4 + r][nt * 16 + l16] = (bf16)(acc[r] + bv4[r]);
            }
        }
        if (kind == 2) {
            int vrow = lane >> 2, vcc = lane & 3;
            bf16x8 chunk = *(const bf16x8*)&vstage[w][vrow][vcc * 8];
            *(bf16x8*)&vT[((size_t)b * CH + (ro - 64) + vrow) * NPIX + n0 + vcc * 8] = chunk;
        }
    }
}

// ---------------------------------------------------------------------------
// Kernel 2: split-K flash attention. R16 = EXACT R10 structure/schedule
// (prefetch at iter-top; QK reg-MFMA + softmax VALU hide the staging latency;
// 2 barriers/iter; kf reg-dbuf; 80 KB LDS; launch_bounds(256,2)).
// Only delta vs R10: softmax exp = single v_exp_f32 (log2e pre-folded).
// Ledger of failed attn variants (do not retry):
//   R11 512-thr blocks -> reg-cap spill; R12 ch-split -> duplicated
//   softmax/LDS; R13 prefetch-after-barrier1 -> LDS port contention in PV;
//   R14 precise exp2f -> ocml bloat; R15 fused-combine threadfence -> L2
//   writeback storm across XCDs (attn 170us).
// ---------------------------------------------------------------------------
template<int S, bool DIRECT>
__global__ __launch_bounds__(256, 2) void attn_kernel(
    const bf16* __restrict__ qp, const bf16* __restrict__ kp,
    const bf16* __restrict__ vT,
    bf16* __restrict__ Opart, float* __restrict__ Lpart,
    float* __restrict__ out)
{
    __shared__ __align__(16) bf16 Vt[2][256][64];   // 64 KB
    __shared__ __align__(16) bf16 PbS[128][64];     // 16 KB, block-shared

    const int t    = threadIdx.x;
    const int bid  = blockIdx.x;
    const int s    = bid % S;
    const int tq   = bid / S;
    const int b    = tq >> 5;
    const int qt   = tq & 31;
    const int n0   = qt << 7;
    const int w    = t >> 6;
    const int lane = t & 63;
    const int l16  = t & 15;
    const int quad = (t & 63) >> 4;
    const int sw   = l16 & 7;
    const int l32  = lane & 31;
    const int h    = lane >> 5;
    const int qh   = w >> 1;            // PV q-half (64 rows)
    const int chb  = (w & 1) * 128;     // PV channel half

    const bf16* qpb = qp + ((size_t)b * NPIX + n0 + w * 32) * CQD;
    bf16x8 qfrag[2];
    qfrag[0] = *(const bf16x8*)(qpb + (size_t)l16 * CQD + quad * 8);
    qfrag[1] = *(const bf16x8*)(qpb + (size_t)(16 + l16) * CQD + quad * 8);

    f32x16 o[2][4];   // [t32 q-tile][ct ch-tile], D[m=q][n=ch]
#pragma unroll
    for (int i = 0; i < 2; ++i)
#pragma unroll
        for (int j = 0; j < 4; ++j)
#pragma unroll
            for (int r = 0; r < 16; ++r) o[i][j][r] = 0.f;
    float lsum[2] = {0.f, 0.f};

    const bf16* kpb = kp + (size_t)b * NPIX * CQD;
    const bf16* vTb = vT + (size_t)b * CH * NPIX;
    const int k0 = s * (NPIX / S);
    const int iters = NPIX / S / 64;

    const int vrow_off = lane >> 3;
    const int vchunk   = (lane & 7) ^ vrow_off;
    auto issue_vt = [&](int buf, int m0) {
#pragma unroll
        for (int j = 0; j < 8; ++j) {
            int rowbase = j * 32 + w * 8;
            const bf16* src = vTb + (size_t)(rowbase + vrow_off) * NPIX + m0 + vchunk * 8;
            GLOAD_LDS16(src, &Vt[buf][rowbase][0]);
        }
    };
    auto load_kf = [&](int m0, bf16x8* kf) {
#pragma unroll
        for (int mt = 0; mt < 4; ++mt)
            kf[mt] = *(const bf16x8*)(kpb + (size_t)(m0 + mt * 16 + l16) * CQD + quad * 8);
    };

    bf16x8 kfa[4], kfb[4];
    issue_vt(0, k0);
    load_kf(k0, kfa);
    __syncthreads();

    for (int mi = 0; mi < iters; ++mi) {
        const int cur = mi & 1;
        const int m0  = k0 + (mi << 6);
        if (mi + 1 < iters) {
            issue_vt(cur ^ 1, m0 + 64);
            load_kf(m0 + 64, kfb);
        }

        // S^T tiles for this wave's 32 q: D[key=mt*16+quad*4+r][q=w*32+g*16+l16]
        f32x4 sv[2][4];
#pragma unroll
        for (int mt = 0; mt < 4; ++mt) {
            f32x4 z = {0.f, 0.f, 0.f, 0.f};
            sv[0][mt] = MFMA16(kfa[mt], qfrag[0], z, 0, 0, 0);
            sv[1][mt] = MFMA16(kfa[mt], qfrag[1], z, 0, 0, 0);
        }

        // p = 2^s (log2e pre-folded, m=0) -> shared PbS[q][key], swizzled
#pragma unroll
        for (int g = 0; g < 2; ++g) {
            float rs = 0.f;
#pragma unroll
            for (int mt = 0; mt < 4; ++mt) {
                bf16x4 pk;
#pragma unroll
                for (int r = 0; r < 4; ++r) {
                    float e = fast_exp2(sv[g][mt][r]);
                    rs += e;
                    pk[r] = (bf16)e;
                }
                int slot = (2 * mt + (quad >> 1)) ^ sw;
                *(bf16x4*)&PbS[w * 32 + g * 16 + l16][slot * 8 + (quad & 1) * 4] = pk;
            }
            lsum[g] += rs;
        }
        __syncthreads();   // PbS visible to all waves (also drains prefetch)

        // PV: A = P[32q x 16k] frags from PbS, B = V[16k x 32ch] from Vt.
        // A/B lane: row/col = lane&31, k = (lane>>5)*8 + j.
        bf16x8 pA[2][4];
#pragma unroll
        for (int t32 = 0; t32 < 2; ++t32)
#pragma unroll
            for (int kg = 0; kg < 4; ++kg) {
                int row = qh * 64 + t32 * 32 + l32;
                pA[t32][kg] = *(const bf16x8*)&PbS[row][((2 * kg + h) ^ (l32 & 7)) * 8];
            }
#pragma unroll
        for (int ct = 0; ct < 4; ++ct) {
            int vrow = chb + ct * 32 + l32;
            bf16x8 vB[4];
#pragma unroll
            for (int kg = 0; kg < 4; ++kg)
                vB[kg] = *(const bf16x8*)&Vt[cur][vrow][((2 * kg + h) ^ (l32 & 7)) * 8];
#pragma unroll
            for (int t32 = 0; t32 < 2; ++t32)
#pragma unroll
                for (int kg = 0; kg < 4; ++kg)
                    o[t32][ct] = MFMA32(pA[t32][kg], vB[kg], o[t32][ct], 0, 0, 0);
        }
        __syncthreads();   // PbS/Vt consumed before next iter's writes/staging
#pragma unroll
        for (int i = 0; i < 4; ++i) kfa[i] = kfb[i];
    }

    // final l: reduce quad partials; rows w*32+g*16+l16
    float l_g[2];
#pragma unroll
    for (int g = 0; g < 2; ++g) {
        float v = lsum[g];
        v += __shfl_xor(v, 16);
        v += __shfl_xor(v, 32);
        l_g[g] = v;
    }
    float* lsh = (float*)PbS;          // PbS dead after final barrier
    if (quad == 0) {
#pragma unroll
        for (int g = 0; g < 2; ++g)
            lsh[w * 32 + g * 16 + l16] = l_g[g];
    }
    __syncthreads();

    const size_t prb2 = ((size_t)s * BATCH + b) * NPIX + n0;
    if (!DIRECT && quad == 0) {
#pragma unroll
        for (int g = 0; g < 2; ++g)
            Lpart[prb2 + w * 32 + g * 16 + l16] = l_g[g];
    }

    // epilogue: D layout row(q) = (reg&3)+8*(reg>>2)+4*h, col(ch) = l32.
    bf16* eb = (bf16*)Vt + (size_t)w * 32 * 136;   // wave-private bounce
#pragma unroll
    for (int t32 = 0; t32 < 2; ++t32) {
        float rinv[16];
#pragma unroll
        for (int reg = 0; reg < 16; ++reg) {
            int q_r = (reg & 3) + 8 * (reg >> 2) + 4 * h;
            rinv[reg] = 1.0f / lsh[qh * 64 + t32 * 32 + q_r];
        }
        if (!DIRECT) {
#pragma unroll
            for (int ct = 0; ct < 4; ++ct)
#pragma unroll
                for (int reg = 0; reg < 16; ++reg) {
                    int q_r = (reg & 3) + 8 * (reg >> 2) + 4 * h;
                    eb[q_r * 136 + ct * 32 + l32] = (bf16)(o[t32][ct][reg] * rinv[reg]);
                }
            // 32 rows x 128 ch = 8192 B = 64 lanes x 16B x 8 passes
            int vrow = lane >> 4, vcc = lane & 15;
#pragma unroll
            for (int p = 0; p < 8; ++p) {
                int row = p * 4 + vrow;
                bf16x8 chunk = *(const bf16x8*)&eb[row * 136 + vcc * 8];
                *(bf16x8*)&Opart[(prb2 + qh * 64 + t32 * 32 + row) * CH +
                                 chb + vcc * 8] = chunk;
            }
        } else {
            float* ob = out + (prb2 + qh * 64 + t32 * 32) * CH + chb;
#pragma unroll
            for (int ct = 0; ct < 4; ++ct)
#pragma unroll
                for (int reg = 0; reg < 16; ++reg) {
                    int q_r = (reg & 3) + 8 * (reg >> 2) + 4 * h;
                    ob[(size_t)q_r * CH + ct * 32 + l32] = o[t32][ct][reg] * rinv[reg];
                }
        }
    }
}

// ---------------------------------------------------------------------------
// Kernel 3: merge S split-K partials: out = sum_s (l_s / sum l) * Ohat_s.
// (R14 ILP version: 16 floats/thread, loads hoisted before FMAs.)
// ---------------------------------------------------------------------------
template<int S>
__global__ __launch_bounds__(256) void combine_kernel(
    const bf16* __restrict__ Opart, const float* __restrict__ Lpart,
    float* __restrict__ out)
{
    int idx  = blockIdx.x * 256 + threadIdx.x;
    int nrow = idx >> 4;
    int cc   = (idx & 15) * 16;
    int b    = nrow >> 12, nin = nrow & 4095;

    size_t pr[S];
    float  ls[S], wsum = 0.f;
#pragma unroll
    for (int s = 0; s < S; ++s) {
        pr[s] = ((size_t)s * BATCH + b) * NPIX + nin;
        ls[s] = Lpart[pr[s]];
        wsum += ls[s];
    }
    float inv = 1.0f / wsum;

    bf16x8 ov[S][2];
#pragma unroll
    for (int s = 0; s < S; ++s) {
        ov[s][0] = *(const bf16x8*)&Opart[pr[s] * CH + cc];
        ov[s][1] = *(const bf16x8*)&Opart[pr[s] * CH + cc + 8];
    }

    float acc[16];
#pragma unroll
    for (int j = 0; j < 16; ++j) acc[j] = 0.f;
#pragma unroll
    for (int s = 0; s < S; ++s) {
        float wn = ls[s] * inv;
#pragma unroll
        for (int k = 0; k < 2; ++k)
#pragma unroll
            for (int j = 0; j < 8; ++j)
                acc[k * 8 + j] += wn * (float)ov[s][k][j];
    }
#pragma unroll
    for (int k = 0; k < 4; ++k) {
        float4 o4 = {acc[4 * k], acc[4 * k + 1], acc[4 * k + 2], acc[4 * k + 3]};
        *(float4*)&out[(size_t)nrow * CH + cc + 4 * k] = o4;
    }
}

extern "C" void kernel_launch(void* const* d_in, const int* in_sizes, int n_in,
                              void* d_out, int out_size, void* d_ws, size_t ws_size,
                              hipStream_t stream) {
    const float* x  = (const float*)d_in[0];
    const float* Wq = (const float*)d_in[1];
    const float* bq = (const float*)d_in[2];
    const float* Wk = (const float*)d_in[3];
    const float* bk = (const float*)d_in[4];
    const float* Wv = (const float*)d_in[5];
    const float* bv = (const float*)d_in[6];
    float* out = (float*)d_out;

    char* ws = (char*)d_ws;
    const size_t qpB   = (size_t)BATCH * NPIX * CQD * 2;   // 1 MB
    const size_t vTB   = (size_t)BATCH * CH * NPIX * 2;    // 8 MB
    const size_t baseB = 2 * qpB + vTB;
    const size_t oprtB = (size_t)BATCH * NPIX * CH * 2;    // 8.4 MB per split
    const size_t mlB   = (size_t)BATCH * NPIX * 4;         // 64 KB per split

    bf16*  qp = (bf16*)ws;
    bf16*  kp = (bf16*)(ws + qpB);
    bf16*  vT = (bf16*)(ws + 2 * qpB);

    proj_kernel<<<dim3(BATCH * (NPIX / 32)), dim3(256), 0, stream>>>(
        x, Wq, bq, Wk, bk, Wv, bv, qp, kp, vT);

    auto need = [&](int S) { return baseB + (size_t)S * (oprtB + mlB); };
    int S = (ws_size >= need(4)) ? 4 : (ws_size >= need(2)) ? 2
          : (ws_size >= need(1)) ? 1 : 0;

    if (S > 0) {
        bf16*  Opart = (bf16*)(ws + baseB);
        float* Lpart = (float*)(ws + baseB + (size_t)S * oprtB);
        if (S == 4) {
            attn_kernel<4, false><<<dim3(128 * 4), dim3(256), 0, stream>>>(
                qp, kp, vT, Opart, Lpart, out);
            combine_kernel<4><<<dim3(1024), dim3(256), 0, stream>>>(Opart, Lpart, out);
        } else if (S == 2) {
            attn_kernel<2, false><<<dim3(128 * 2), dim3(256), 0, stream>>>(
                qp, kp, vT, Opart, Lpart, out);
            combine_kernel<2><<<dim3(1024), dim3(256), 0, stream>>>(Opart, Lpart, out);
        } else {
            attn_kernel<1, false><<<dim3(128), dim3(256), 0, stream>>>(
                qp, kp, vT, Opart, Lpart, out);
            combine_kernel<1><<<dim3(1024), dim3(256), 0, stream>>>(Opart, Lpart, out);
        }
    } else {
        attn_kernel<1, true><<<dim3(128), dim3(256), 0, stream>>>(
            qp, kp, vT, nullptr, nullptr, out);
    }
}

// Round 7
// 142.719 us; speedup vs baseline: 1.6097x; 1.0592x over previous
//
#include <hip/hip_runtime.h>

#define BATCH 4
#define CH    256
#define NPIX  4096
#define CQD   32

typedef __bf16 bf16;
typedef bf16 bf16x8 __attribute__((ext_vector_type(8)));
typedef bf16 bf16x4 __attribute__((ext_vector_type(4)));
typedef float f32x4 __attribute__((ext_vector_type(4)));
typedef float f32x16 __attribute__((ext_vector_type(16)));

#define MFMA16 __builtin_amdgcn_mfma_f32_16x16x32_bf16
#define MFMA32 __builtin_amdgcn_mfma_f32_32x32x16_bf16

#define GLOAD_LDS16(g, l) __builtin_amdgcn_global_load_lds( \
    (const __attribute__((address_space(1))) void*)(g),     \
    (__attribute__((address_space(3))) void*)(l), 16, 0, 0)

// Single-instruction 2^x (v_exp_f32). Verified: attn 52.5 -> 50.3 us,
// VALUBusy 29.6 -> 25.7% (R16). Precise exp2f() is a ~6-op ocml sequence
// (R14 regression); __expf is v_mul+v_exp (R10 baseline).
__device__ __forceinline__ float fast_exp2(float x) {
#if __has_builtin(__builtin_amdgcn_exp2f)
    return __builtin_amdgcn_exp2f(x);
#else
    return __expf(x * 0.69314718055994530942f);
#endif
}

// q-scale: 1/sqrt(4096) = 1/64, with log2(e) folded so softmax is bare 2^x.
#define QSCALE (0.015625f * 1.44269504088896340736f)

// ---------------------------------------------------------------------------
// Kernel 0: pack weights to bf16, stacked [320][256] (q-scale+log2e folded).
// STANDALONE (R16 post-mortem: fusing this into proj makes all 512 proj
// blocks re-read 327 KB f32 weights + re-convert -> +10 us. One-pass prep
// amortizes the conversion over the whole launch.)
// ---------------------------------------------------------------------------
__global__ __launch_bounds__(256) void prep_kernel(
    const float* __restrict__ Wq, const float* __restrict__ bq,
    const float* __restrict__ Wk, const float* __restrict__ bk,
    const float* __restrict__ Wv, const float* __restrict__ bv,
    bf16* __restrict__ Wb, float* __restrict__ bb)
{
    int r = blockIdx.x, c = threadIdx.x;
    const float* W; const float* bs; float sc; int rr;
    if (r < 32)      { W = Wq; bs = bq; sc = QSCALE; rr = r; }
    else if (r < 64) { W = Wk; bs = bk; sc = 1.0f;   rr = r - 32; }
    else             { W = Wv; bs = bv; sc = 1.0f;   rr = r - 64; }
    Wb[(size_t)r * CH + c] = (bf16)(W[(size_t)rr * CH + c] * sc);
    if (c == 0) bb[r] = bs[rr] * sc;
}

// ---------------------------------------------------------------------------
// Kernel 1: fused 1x1-conv projections via MFMA (R6/R14 version: bf16
// weight fragments from prepped Wb).
// ---------------------------------------------------------------------------
__global__ __launch_bounds__(256) void proj_kernel(
    const float* __restrict__ x,
    const bf16* __restrict__ Wb, const float* __restrict__ bb,
    bf16* __restrict__ qp, bf16* __restrict__ kp, bf16* __restrict__ vT)
{
    __shared__ __align__(16) bf16 xT[32][264];
    __shared__ __align__(16) bf16 vstage[4][16][40];

    const int t  = threadIdx.x;
    const int b  = blockIdx.x >> 7;
    const int n0 = (blockIdx.x & 127) << 5;
    const int w    = t >> 6;
    const int lane = t & 63;
    const int l16  = t & 15;
    const int quad = (t & 63) >> 4;

    const float* xb = x + (size_t)b * CH * NPIX;
#pragma unroll
    for (int j = 0; j < 8; ++j) {
        int id = t + j * 256;
        int c  = id >> 3;
        int n4 = (id & 7) << 2;
        float4 vv = *(const float4*)(xb + (size_t)c * NPIX + n0 + n4);
        xT[n4 + 0][c] = (bf16)vv.x;
        xT[n4 + 1][c] = (bf16)vv.y;
        xT[n4 + 2][c] = (bf16)vv.z;
        xT[n4 + 3][c] = (bf16)vv.w;
    }
    __syncthreads();

    for (int rt = 0; rt < 5; ++rt) {
        int ro = w * 80 + rt * 16;
        int kind = (ro < 32) ? 0 : (ro < 64) ? 1 : 2;

        bf16x8 afrag[8];
        const bf16* wrow = Wb + (size_t)(ro + l16) * CH + quad * 8;
#pragma unroll
        for (int kc = 0; kc < 8; ++kc)
            afrag[kc] = *(const bf16x8*)(wrow + kc * 32);
        float bv4[4];
#pragma unroll
        for (int r = 0; r < 4; ++r) bv4[r] = bb[ro + quad * 4 + r];

#pragma unroll
        for (int nt = 0; nt < 2; ++nt) {
            f32x4 acc = {0.f, 0.f, 0.f, 0.f};
#pragma unroll
            for (int kc = 0; kc < 8; ++kc) {
                bf16x8 bfr = *(const bf16x8*)&xT[nt * 16 + l16][kc * 32 + quad * 8];
                acc = MFMA16(afrag[kc], bfr, acc, 0, 0, 0);
            }
            if (kind != 2) {
                bf16x4 pk;
#pragma unroll
                for (int r = 0; r < 4; ++r)
                    pk[r] = (bf16)(acc[r] + bv4[r]);
                int n = n0 + nt * 16 + l16;
                int col = (kind == 0 ? ro : ro - 32) + quad * 4;
                bf16* dst = (kind == 0) ? qp : kp;
                *(bf16x4*)&dst[((size_t)b * NPIX + n) * CQD + col] = pk;
            } else {
#pragma unroll
                for (int r = 0; r < 4; ++r)
                    vstage[w][quad * 4 + r][nt * 16 + l16] = (bf16)(acc[r] + bv4[r]);
            }
        }
        if (kind == 2) {
            int vrow = lane >> 2, vcc = lane & 3;
            bf16x8 chunk = *(const bf16x8*)&vstage[w][vrow][vcc * 8];
            *(bf16x8*)&vT[((size_t)b * CH + (ro - 64) + vrow) * NPIX + n0 + vcc * 8] = chunk;
        }
    }
}

// ---------------------------------------------------------------------------
// Kernel 2: split-K flash attention = R10 structure/schedule + fast_exp2
// softmax (log2e pre-folded by prep). Measured 50.2-50.5 us (R16).
// Ledger of failed variants (do not retry): R11 512-thr blocks (reg-cap
// spill); R12 ch-split (duplicated softmax/LDS); R13 prefetch-after-barrier1
// (LDS port contention in PV); R14 precise exp2f (ocml bloat); R15
// fused-combine threadfence (cross-XCD L2 writeback storm).
// ---------------------------------------------------------------------------
template<int S, bool DIRECT>
__global__ __launch_bounds__(256, 2) void attn_kernel(
    const bf16* __restrict__ qp, const bf16* __restrict__ kp,
    const bf16* __restrict__ vT,
    bf16* __restrict__ Opart, float* __restrict__ Lpart,
    float* __restrict__ out)
{
    __shared__ __align__(16) bf16 Vt[2][256][64];   // 64 KB
    __shared__ __align__(16) bf16 PbS[128][64];     // 16 KB, block-shared

    const int t    = threadIdx.x;
    const int bid  = blockIdx.x;
    const int s    = bid % S;
    const int tq   = bid / S;
    const int b    = tq >> 5;
    const int qt   = tq & 31;
    const int n0   = qt << 7;
    const int w    = t >> 6;
    const int lane = t & 63;
    const int l16  = t & 15;
    const int quad = (t & 63) >> 4;
    const int sw   = l16 & 7;
    const int l32  = lane & 31;
    const int h    = lane >> 5;
    const int qh   = w >> 1;            // PV q-half (64 rows)
    const int chb  = (w & 1) * 128;     // PV channel half

    const bf16* qpb = qp + ((size_t)b * NPIX + n0 + w * 32) * CQD;
    bf16x8 qfrag[2];
    qfrag[0] = *(const bf16x8*)(qpb + (size_t)l16 * CQD + quad * 8);
    qfrag[1] = *(const bf16x8*)(qpb + (size_t)(16 + l16) * CQD + quad * 8);

    f32x16 o[2][4];   // [t32 q-tile][ct ch-tile], D[m=q][n=ch]
#pragma unroll
    for (int i = 0; i < 2; ++i)
#pragma unroll
        for (int j = 0; j < 4; ++j)
#pragma unroll
            for (int r = 0; r < 16; ++r) o[i][j][r] = 0.f;
    float lsum[2] = {0.f, 0.f};

    const bf16* kpb = kp + (size_t)b * NPIX * CQD;
    const bf16* vTb = vT + (size_t)b * CH * NPIX;
    const int k0 = s * (NPIX / S);
    const int iters = NPIX / S / 64;

    const int vrow_off = lane >> 3;
    const int vchunk   = (lane & 7) ^ vrow_off;
    auto issue_vt = [&](int buf, int m0) {
#pragma unroll
        for (int j = 0; j < 8; ++j) {
            int rowbase = j * 32 + w * 8;
            const bf16* src = vTb + (size_t)(rowbase + vrow_off) * NPIX + m0 + vchunk * 8;
            GLOAD_LDS16(src, &Vt[buf][rowbase][0]);
        }
    };
    auto load_kf = [&](int m0, bf16x8* kf) {
#pragma unroll
        for (int mt = 0; mt < 4; ++mt)
            kf[mt] = *(const bf16x8*)(kpb + (size_t)(m0 + mt * 16 + l16) * CQD + quad * 8);
    };

    bf16x8 kfa[4], kfb[4];
    issue_vt(0, k0);
    load_kf(k0, kfa);
    __syncthreads();

    for (int mi = 0; mi < iters; ++mi) {
        const int cur = mi & 1;
        const int m0  = k0 + (mi << 6);
        if (mi + 1 < iters) {
            issue_vt(cur ^ 1, m0 + 64);
            load_kf(m0 + 64, kfb);
        }

        // S^T tiles for this wave's 32 q: D[key=mt*16+quad*4+r][q=w*32+g*16+l16]
        f32x4 sv[2][4];
#pragma unroll
        for (int mt = 0; mt < 4; ++mt) {
            f32x4 z = {0.f, 0.f, 0.f, 0.f};
            sv[0][mt] = MFMA16(kfa[mt], qfrag[0], z, 0, 0, 0);
            sv[1][mt] = MFMA16(kfa[mt], qfrag[1], z, 0, 0, 0);
        }

        // p = 2^s (log2e pre-folded, m=0) -> shared PbS[q][key], swizzled
#pragma unroll
        for (int g = 0; g < 2; ++g) {
            float rs = 0.f;
#pragma unroll
            for (int mt = 0; mt < 4; ++mt) {
                bf16x4 pk;
#pragma unroll
                for (int r = 0; r < 4; ++r) {
                    float e = fast_exp2(sv[g][mt][r]);
                    rs += e;
                    pk[r] = (bf16)e;
                }
                int slot = (2 * mt + (quad >> 1)) ^ sw;
                *(bf16x4*)&PbS[w * 32 + g * 16 + l16][slot * 8 + (quad & 1) * 4] = pk;
            }
            lsum[g] += rs;
        }
        __syncthreads();   // PbS visible to all waves (also drains prefetch)

        // PV: A = P[32q x 16k] frags from PbS, B = V[16k x 32ch] from Vt.
        // A/B lane: row/col = lane&31, k = (lane>>5)*8 + j.
        bf16x8 pA[2][4];
#pragma unroll
        for (int t32 = 0; t32 < 2; ++t32)
#pragma unroll
            for (int kg = 0; kg < 4; ++kg) {
                int row = qh * 64 + t32 * 32 + l32;
                pA[t32][kg] = *(const bf16x8*)&PbS[row][((2 * kg + h) ^ (l32 & 7)) * 8];
            }
#pragma unroll
        for (int ct = 0; ct < 4; ++ct) {
            int vrow = chb + ct * 32 + l32;
            bf16x8 vB[4];
#pragma unroll
            for (int kg = 0; kg < 4; ++kg)
                vB[kg] = *(const bf16x8*)&Vt[cur][vrow][((2 * kg + h) ^ (l32 & 7)) * 8];
#pragma unroll
            for (int t32 = 0; t32 < 2; ++t32)
#pragma unroll
                for (int kg = 0; kg < 4; ++kg)
                    o[t32][ct] = MFMA32(pA[t32][kg], vB[kg], o[t32][ct], 0, 0, 0);
        }
        __syncthreads();   // PbS/Vt consumed before next iter's writes/staging
#pragma unroll
        for (int i = 0; i < 4; ++i) kfa[i] = kfb[i];
    }

    // final l: reduce quad partials; rows w*32+g*16+l16
    float l_g[2];
#pragma unroll
    for (int g = 0; g < 2; ++g) {
        float v = lsum[g];
        v += __shfl_xor(v, 16);
        v += __shfl_xor(v, 32);
        l_g[g] = v;
    }
    float* lsh = (float*)PbS;          // PbS dead after final barrier
    if (quad == 0) {
#pragma unroll
        for (int g = 0; g < 2; ++g)
            lsh[w * 32 + g * 16 + l16] = l_g[g];
    }
    __syncthreads();

    const size_t prb2 = ((size_t)s * BATCH + b) * NPIX + n0;
    if (!DIRECT && quad == 0) {
#pragma unroll
        for (int g = 0; g < 2; ++g)
            Lpart[prb2 + w * 32 + g * 16 + l16] = l_g[g];
    }

    // epilogue: D layout row(q) = (reg&3)+8*(reg>>2)+4*h, col(ch) = l32.
    bf16* eb = (bf16*)Vt + (size_t)w * 32 * 136;   // wave-private bounce
#pragma unroll
    for (int t32 = 0; t32 < 2; ++t32) {
        float rinv[16];
#pragma unroll
        for (int reg = 0; reg < 16; ++reg) {
            int q_r = (reg & 3) + 8 * (reg >> 2) + 4 * h;
            rinv[reg] = 1.0f / lsh[qh * 64 + t32 * 32 + q_r];
        }
        if (!DIRECT) {
#pragma unroll
            for (int ct = 0; ct < 4; ++ct)
#pragma unroll
                for (int reg = 0; reg < 16; ++reg) {
                    int q_r = (reg & 3) + 8 * (reg >> 2) + 4 * h;
                    eb[q_r * 136 + ct * 32 + l32] = (bf16)(o[t32][ct][reg] * rinv[reg]);
                }
            // 32 rows x 128 ch = 8192 B = 64 lanes x 16B x 8 passes
            int vrow = lane >> 4, vcc = lane & 15;
#pragma unroll
            for (int p = 0; p < 8; ++p) {
                int row = p * 4 + vrow;
                bf16x8 chunk = *(const bf16x8*)&eb[row * 136 + vcc * 8];
                *(bf16x8*)&Opart[(prb2 + qh * 64 + t32 * 32 + row) * CH +
                                 chb + vcc * 8] = chunk;
            }
        } else {
            float* ob = out + (prb2 + qh * 64 + t32 * 32) * CH + chb;
#pragma unroll
            for (int ct = 0; ct < 4; ++ct)
#pragma unroll
                for (int reg = 0; reg < 16; ++reg) {
                    int q_r = (reg & 3) + 8 * (reg >> 2) + 4 * h;
                    ob[(size_t)q_r * CH + ct * 32 + l32] = o[t32][ct][reg] * rinv[reg];
                }
        }
    }
}

// ---------------------------------------------------------------------------
// Kernel 3: merge S split-K partials: out = sum_s (l_s / sum l) * Ohat_s.
// (R14 ILP version: 16 floats/thread, loads hoisted before FMAs.)
// ---------------------------------------------------------------------------
template<int S>
__global__ __launch_bounds__(256) void combine_kernel(
    const bf16* __restrict__ Opart, const float* __restrict__ Lpart,
    float* __restrict__ out)
{
    int idx  = blockIdx.x * 256 + threadIdx.x;
    int nrow = idx >> 4;
    int cc   = (idx & 15) * 16;
    int b    = nrow >> 12, nin = nrow & 4095;

    size_t pr[S];
    float  ls[S], wsum = 0.f;
#pragma unroll
    for (int s = 0; s < S; ++s) {
        pr[s] = ((size_t)s * BATCH + b) * NPIX + nin;
        ls[s] = Lpart[pr[s]];
        wsum += ls[s];
    }
    float inv = 1.0f / wsum;

    bf16x8 ov[S][2];
#pragma unroll
    for (int s = 0; s < S; ++s) {
        ov[s][0] = *(const bf16x8*)&Opart[pr[s] * CH + cc];
        ov[s][1] = *(const bf16x8*)&Opart[pr[s] * CH + cc + 8];
    }

    float acc[16];
#pragma unroll
    for (int j = 0; j < 16; ++j) acc[j] = 0.f;
#pragma unroll
    for (int s = 0; s < S; ++s) {
        float wn = ls[s] * inv;
#pragma unroll
        for (int k = 0; k < 2; ++k)
#pragma unroll
            for (int j = 0; j < 8; ++j)
                acc[k * 8 + j] += wn * (float)ov[s][k][j];
    }
#pragma unroll
    for (int k = 0; k < 4; ++k) {
        float4 o4 = {acc[4 * k], acc[4 * k + 1], acc[4 * k + 2], acc[4 * k + 3]};
        *(float4*)&out[(size_t)nrow * CH + cc + 4 * k] = o4;
    }
}

extern "C" void kernel_launch(void* const* d_in, const int* in_sizes, int n_in,
                              void* d_out, int out_size, void* d_ws, size_t ws_size,
                              hipStream_t stream) {
    const float* x  = (const float*)d_in[0];
    const float* Wq = (const float*)d_in[1];
    const float* bq = (const float*)d_in[2];
    const float* Wk = (const float*)d_in[3];
    const float* bk = (const float*)d_in[4];
    const float* Wv = (const float*)d_in[5];
    const float* bv = (const float*)d_in[6];
    float* out = (float*)d_out;

    char* ws = (char*)d_ws;
    const size_t qpB   = (size_t)BATCH * NPIX * CQD * 2;   // 1 MB
    const size_t vTB   = (size_t)BATCH * CH * NPIX * 2;    // 8 MB
    const size_t WbB   = (size_t)320 * CH * 2;             // 160 KB
    const size_t bbB   = 320 * 4 + 768;                    // padded
    const size_t baseB = 2 * qpB + vTB + WbB + bbB;
    const size_t oprtB = (size_t)BATCH * NPIX * CH * 2;    // 8.4 MB per split
    const size_t mlB   = (size_t)BATCH * NPIX * 4;         // 64 KB per split

    bf16*  qp = (bf16*)ws;
    bf16*  kp = (bf16*)(ws + qpB);
    bf16*  vT = (bf16*)(ws + 2 * qpB);
    bf16*  Wb = (bf16*)(ws + 2 * qpB + vTB);
    float* bb = (float*)(ws + 2 * qpB + vTB + WbB);

    prep_kernel<<<dim3(320), dim3(256), 0, stream>>>(Wq, bq, Wk, bk, Wv, bv, Wb, bb);
    proj_kernel<<<dim3(BATCH * (NPIX / 32)), dim3(256), 0, stream>>>(
        x, Wb, bb, qp, kp, vT);

    auto need = [&](int S) { return baseB + (size_t)S * (oprtB + mlB); };
    int S = (ws_size >= need(4)) ? 4 : (ws_size >= need(2)) ? 2
          : (ws_size >= need(1)) ? 1 : 0;

    if (S > 0) {
        bf16*  Opart = (bf16*)(ws + baseB);
        float* Lpart = (float*)(ws + baseB + (size_t)S * oprtB);
        if (S == 4) {
            attn_kernel<4, false><<<dim3(128 * 4), dim3(256), 0, stream>>>(
                qp, kp, vT, Opart, Lpart, out);
            combine_kernel<4><<<dim3(1024), dim3(256), 0, stream>>>(Opart, Lpart, out);
        } else if (S == 2) {
            attn_kernel<2, false><<<dim3(128 * 2), dim3(256), 0, stream>>>(
                qp, kp, vT, Opart, Lpart, out);
            combine_kernel<2><<<dim3(1024), dim3(256), 0, stream>>>(Opart, Lpart, out);
        } else {
            attn_kernel<1, false><<<dim3(128), dim3(256), 0, stream>>>(
                qp, kp, vT, Opart, Lpart, out);
            combine_kernel<1><<<dim3(1024), dim3(256), 0, stream>>>(Opart, Lpart, out);
        }
    } else {
        attn_kernel<1, true><<<dim3(128), dim3(256), 0, stream>>>(
            qp, kp, vT, nullptr, nullptr, out);
    }
}